// Round 4
// baseline (1433.594 us; speedup 1.0000x reference)
//
#include <hip/hip_runtime.h>
#include <hip/hip_bf16.h>
#include <cstdint>
#include <cstddef>

#define NN 8192
#define BM 128
#define BN 128
#define BK 32

typedef unsigned short u16;
typedef unsigned int   u32;
typedef __attribute__((ext_vector_type(8))) short bf16x8;   // 8 bf16 = 4 VGPRs
typedef __attribute__((ext_vector_type(4))) unsigned short u16x4;
typedef __attribute__((ext_vector_type(4))) float f32x4;
typedef __attribute__((ext_vector_type(4))) float floatx4;

__device__ __forceinline__ void gload_lds16(const u16* g, u16* l) {
    __builtin_amdgcn_global_load_lds(
        (const __attribute__((address_space(1))) unsigned int*)g,
        (__attribute__((address_space(3))) unsigned int*)l,
        16, 0, 0);
}

__device__ __forceinline__ u16 f32_to_bf16(float f) {
    __hip_bfloat16 h = __float2bfloat16(f);   // RNE
    return *(u16*)&h;
}

__device__ __forceinline__ void write_zero_tile_f32(float* C, int bm, int bn, int t) {
    f32x4 z = (f32x4){0.f, 0.f, 0.f, 0.f};
    #pragma unroll
    for (int p = 0; p < 16; ++p) {
        int c  = t + p * 256;        // f32x4 chunk id; 32 chunks per 128-wide row
        int r  = c >> 5;
        int ch = c & 31;
        *(f32x4*)(C + (size_t)(bm * BM + r) * NN + bn * BN + ch * 4) = z;
    }
}

__device__ __forceinline__ void store_acc_f32(float* C, const floatx4 (&acc)[4][4],
                                              int bm, int bn, int wm, int wn, int lane) {
    // C/D layout col=lane&15, row=(lane>>4)*4+reg (m89/m91-verified)
    const int col0 = bn * BN + wn * 64 + (lane & 15);
    const int rowq = (lane >> 4) * 4;
    #pragma unroll
    for (int i = 0; i < 4; ++i) {
        int rbase = bm * BM + wm * 64 + i * 16 + rowq;
        #pragma unroll
        for (int j = 0; j < 4; ++j) {
            int col = col0 + j * 16;
            #pragma unroll
            for (int r = 0; r < 4; ++r) {
                int row = rbase + r;
                float v = acc[i][j][r];
                if (col < row) v = 0.0f;       // triu mask
                C[(size_t)row * NN + col] = v;
            }
        }
    }
}

// ================= Tier A: prep kernels =================
// A (f32) -> Abf (bf16), elementwise
__global__ __launch_bounds__(256) void cvt_a(const float* __restrict__ A,
                                             u16* __restrict__ Abf) {
    size_t i = ((size_t)blockIdx.x * 256 + threadIdx.x) * 8;
    f32x4 v0 = *(const f32x4*)(A + i);
    f32x4 v1 = *(const f32x4*)(A + i + 4);
    bf16x8 o;
    #pragma unroll
    for (int e = 0; e < 4; ++e) { o[e] = (short)f32_to_bf16(v0[e]); o[e+4] = (short)f32_to_bf16(v1[e]); }
    *(bf16x8*)(Abf + i) = o;
}

// B (f32, K x N) -> BTbf (bf16, N x K)
__global__ __launch_bounds__(256) void cvtT_b(const float* __restrict__ B,
                                              u16* __restrict__ BT) {
    __shared__ alignas(16) u16 tile[64][72];   // 144B row stride, 16B-aligned
    const int bi = blockIdx.y;   // k tile
    const int bj = blockIdx.x;   // n tile
    const int t  = threadIdx.x;

    #pragma unroll
    for (int p = 0; p < 4; ++p) {
        int r  = p * 16 + (t >> 4);          // 0..63
        int c4 = t & 15;                     // f32x4 chunk along n
        f32x4 v = *(const f32x4*)(B + (size_t)(bi * 64 + r) * NN + bj * 64 + c4 * 4);
        #pragma unroll
        for (int e = 0; e < 4; ++e)
            tile[c4 * 4 + e][r] = f32_to_bf16(v[e]);
    }
    __syncthreads();
    #pragma unroll
    for (int p = 0; p < 2; ++p) {
        int c  = t + p * 256;
        int cc = c >> 3;
        int ro = c & 7;
        bf16x8 v = *(const bf16x8*)&tile[cc][ro * 8];
        *(bf16x8*)(BT + (size_t)(bj * 64 + cc) * NN + bi * 64 + ro * 8) = v;
    }
}

// ================= Tier A: GEMM (m97 structure, bf16 staging) =================
__global__ __launch_bounds__(256) void gemm_triu_ws(const u16* __restrict__ A,
                                                    const u16* __restrict__ BT,
                                                    float* __restrict__ C) {
    const int bn = blockIdx.x;
    const int bm = blockIdx.y;
    const int t  = threadIdx.x;

    if (bn < bm) { write_zero_tile_f32(C, bm, bn, t); return; }

    __shared__ alignas(16) u16 As[BM * BK];
    __shared__ alignas(16) u16 Bs[BN * BK];

    const int lane = t & 63;
    const int wave = t >> 6;
    const int wm = wave >> 1;
    const int wn = wave & 1;

    const int sr = lane >> 2;
    const int sc = lane & 3;
    const u16* gA = A  + (size_t)(bm * BM + wave * 16 + sr) * NN + sc * 8;
    const u16* gB = BT + (size_t)(bn * BN + wave * 16 + sr) * NN + sc * 8;
    u16* lA = As + (wave * 16) * BK;
    u16* lB = Bs + (wave * 16) * BK;

    floatx4 acc[4][4];
    #pragma unroll
    for (int i = 0; i < 4; ++i)
        #pragma unroll
        for (int j = 0; j < 4; ++j)
            acc[i][j] = (floatx4){0.f, 0.f, 0.f, 0.f};

    const int fr = lane & 15;
    const int fo = (lane >> 4) * 8;
    const bf16x8* fA0 = (const bf16x8*)(As + (wm * 64 + fr) * BK + fo);
    const bf16x8* fB0 = (const bf16x8*)(Bs + (wn * 64 + fr) * BK + fo);

    for (int k0 = 0; k0 < NN; k0 += BK) {
        __syncthreads();
        gload_lds16(gA,                 lA);
        gload_lds16(gA + (size_t)64*NN, lA + 64 * BK);
        gload_lds16(gB,                 lB);
        gload_lds16(gB + (size_t)64*NN, lB + 64 * BK);
        gA += BK; gB += BK;
        __syncthreads();

        bf16x8 af[4], bf[4];
        #pragma unroll
        for (int i = 0; i < 4; ++i) af[i] = fA0[i * 16 * BK / 8];
        #pragma unroll
        for (int j = 0; j < 4; ++j) bf[j] = fB0[j * 16 * BK / 8];
        #pragma unroll
        for (int i = 0; i < 4; ++i)
            #pragma unroll
            for (int j = 0; j < 4; ++j)
                acc[i][j] = __builtin_amdgcn_mfma_f32_16x16x32_bf16(af[i], bf[j], acc[i][j], 0, 0, 0);
    }
    store_acc_f32(C, acc, bm, bn, wm, wn, lane);
}

// ================= Tier C: workspace-free, convert during staging =================
__global__ __launch_bounds__(256) void gemm_triu_nows(const float* __restrict__ A,
                                                      const float* __restrict__ B,
                                                      float* __restrict__ C) {
    // L2-friendly swizzle: 8 bm per bn sweep
    const int lin = blockIdx.y * 64 + blockIdx.x;
    const int rg  = lin >> 9;
    const int wi  = lin & 511;
    const int bm  = (rg << 3) | (wi & 7);
    const int bn  = wi >> 3;
    const int t   = threadIdx.x;

    if (bn < bm) { write_zero_tile_f32(C, bm, bn, t); return; }

    __shared__ alignas(16) u16 As[BM * BK];
    __shared__ alignas(16) u16 Bs[BN * BK];   // [n][k], dword-XOR-swizzled within each row
    u32* Bsd = (u32*)Bs;

    const int lane = t & 63;
    const int wave = t >> 6;
    const int wm = wave >> 1;
    const int wn = wave & 1;

    // A staging: pass p covers rows p*32..p*32+31; thread -> (row, f32x4 k-chunk)
    const int ar = t >> 3;    // 0..31
    const int ac = t & 7;     // 0..7
    const float* gA = A + (size_t)(bm * BM + ar) * NN + ac * 4;
    // B staging: thread -> k-pair dk, n-chunk co; pass p adds 64 to n
    const int dk = t >> 4;    // 0..15
    const int co = t & 15;    // 0..15
    const int dkx = dk ^ ((co & 3) << 2);   // bank swizzle
    const float* gB = B + (size_t)(2 * dk) * NN + bn * BN + co * 4;

    floatx4 acc[4][4];
    #pragma unroll
    for (int i = 0; i < 4; ++i)
        #pragma unroll
        for (int j = 0; j < 4; ++j)
            acc[i][j] = (floatx4){0.f, 0.f, 0.f, 0.f};

    const int fr = lane & 15;
    const int q  = lane >> 4;
    const bf16x8* fA0 = (const bf16x8*)(As + (wm * 64 + fr) * BK + q * 8);

    f32x4 pa[4], pb0[2], pb1[2];
    #pragma unroll
    for (int p = 0; p < 4; ++p) pa[p] = *(const f32x4*)(gA + (size_t)p * 32 * NN);
    #pragma unroll
    for (int p = 0; p < 2; ++p) {
        pb0[p] = *(const f32x4*)(gB + p * 64);
        pb1[p] = *(const f32x4*)(gB + NN + p * 64);
    }

    for (int k0 = 0; k0 < NN; k0 += BK) {
        __syncthreads();                           // previous fragments consumed
        // stage A (bf16)
        #pragma unroll
        for (int p = 0; p < 4; ++p) {
            u16x4 h;
            #pragma unroll
            for (int e = 0; e < 4; ++e) h[e] = f32_to_bf16(pa[p][e]);
            *(u16x4*)(As + (p * 32 + ar) * BK + ac * 4) = h;   // ds_write_b64
        }
        // stage B transposed (bf16 pairs packed in dwords, swizzled)
        #pragma unroll
        for (int p = 0; p < 2; ++p) {
            #pragma unroll
            for (int e = 0; e < 4; ++e) {
                u32 d = (u32)f32_to_bf16(pb0[p][e]) | ((u32)f32_to_bf16(pb1[p][e]) << 16);
                Bsd[((p * 16 + co) * 4 + e) * (BK / 2) + dkx] = d;
            }
        }
        __syncthreads();

        // prefetch next K-slice (hides behind MFMA)
        if (k0 + BK < NN) {
            gA += BK;
            gB += (size_t)BK * NN;
            #pragma unroll
            for (int p = 0; p < 4; ++p) pa[p] = *(const f32x4*)(gA + (size_t)p * 32 * NN);
            #pragma unroll
            for (int p = 0; p < 2; ++p) {
                pb0[p] = *(const f32x4*)(gB + p * 64);
                pb1[p] = *(const f32x4*)(gB + NN + p * 64);
            }
        }

        bf16x8 af[4], bf[4];
        #pragma unroll
        for (int i = 0; i < 4; ++i) af[i] = fA0[i * 16 * BK / 8];
        #pragma unroll
        for (int j = 0; j < 4; ++j) {
            int n  = wn * 64 + j * 16 + fr;
            int qx = q ^ ((n >> 2) & 3);
            bf[j] = *(const bf16x8*)(Bs + n * BK + qx * 8);
        }
        #pragma unroll
        for (int i = 0; i < 4; ++i)
            #pragma unroll
            for (int j = 0; j < 4; ++j)
                acc[i][j] = __builtin_amdgcn_mfma_f32_16x16x32_bf16(af[i], bf[j], acc[i][j], 0, 0, 0);
    }
    store_acc_f32(C, acc, bm, bn, wm, wn, lane);
}

extern "C" void kernel_launch(void* const* d_in, const int* in_sizes, int n_in,
                              void* d_out, int out_size, void* d_ws, size_t ws_size,
                              hipStream_t stream) {
    const float* A = (const float*)d_in[0];
    const float* B = (const float*)d_in[1];
    float* C = (float*)d_out;

    const size_t half = (size_t)NN * NN * sizeof(u16);   // 128 MiB
    if (ws_size >= 2 * half) {
        u16* Abf = (u16*)d_ws;
        u16* BTbf = (u16*)d_ws + (size_t)NN * NN;
        cvt_a<<<32768, 256, 0, stream>>>(A, Abf);
        cvtT_b<<<dim3(128, 128), 256, 0, stream>>>(B, BTbf);
        gemm_triu_ws<<<dim3(64, 64), 256, 0, stream>>>(Abf, BTbf, C);
    } else {
        gemm_triu_nows<<<dim3(64, 64), 256, 0, stream>>>(A, B, C);
    }
}